// Round 1
// baseline (23.007 us; speedup 1.0000x reference)
//
#include <hip/hip_runtime.h>
#include <hip/hip_bf16.h>

typedef __attribute__((ext_vector_type(8))) short short8_t;
typedef __attribute__((ext_vector_type(4))) float f32x4;

static __device__ __forceinline__ unsigned short f2bf(float f) {
    unsigned int u = __float_as_uint(f);
    unsigned int r = u + 0x7fffu + ((u >> 16) & 1u);   // RNE (finite inputs)
    return (unsigned short)(r >> 16);
}

// Convert f32 [rows_valid][128] -> bf16 [rows_total][128] (zero-padded), plus f32 row norms.
// 8 rows/block, 32 lanes/row, float4 per lane.
__global__ __launch_bounds__(256) void prep_kernel(
        const float* __restrict__ src, unsigned short* __restrict__ dst,
        float* __restrict__ sq, int rows_valid, int rows_total) {
    int t = threadIdx.x;
    int row = blockIdx.x * 8 + (t >> 5);
    int lane32 = t & 31;
    if (row >= rows_total) return;
    float4 v = make_float4(0.f, 0.f, 0.f, 0.f);
    if (row < rows_valid)
        v = reinterpret_cast<const float4*>(src + (size_t)row * 128)[lane32];
    ushort4 b;
    b.x = f2bf(v.x); b.y = f2bf(v.y); b.z = f2bf(v.z); b.w = f2bf(v.w);
    reinterpret_cast<ushort4*>(dst + (size_t)row * 128)[lane32] = b;
    float s = v.x*v.x + v.y*v.y + v.z*v.z + v.w*v.w;
    #pragma unroll
    for (int m = 16; m >= 1; m >>= 1) s += __shfl_xor(s, m, 64);
    if (lane32 == 0) sq[row] = s;
}

#define BM 128
#define BN 64
#define LDA 136   // bf16 elems per LDS row: 128 + 8 pad (16B slot shift per row)

// out[m][c] = 2*dot(x[m],P[c]) - xsq[m] - psq[c], for c < 1000.
__global__ __launch_bounds__(256) void gemm_kernel(
        const unsigned short* __restrict__ A,   // [8192][128] bf16 bits
        const unsigned short* __restrict__ B,   // [1024][128] bf16 bits (padded)
        const float* __restrict__ xsq, const float* __restrict__ psq,
        float* __restrict__ out) {
    __shared__ unsigned short As[BM][LDA];
    __shared__ unsigned short Bs[BN][LDA];
    __shared__ float xq_s[BM];
    __shared__ float pq_s[BN];

    int t = threadIdx.x;
    int bm = blockIdx.x & 63;        // 64 M-tiles
    int bn = blockIdx.x >> 6;        // 16 N-tiles
    const int rowA0 = bm * BM;
    const int rowB0 = bn * BN;

    // Stage A tile: 128 rows x 128 bf16 (16B chunks, 16 chunks/row)
    #pragma unroll
    for (int it = 0; it < 8; ++it) {
        int idx = it * 256 + t;
        int r = idx >> 4;
        int c = (idx & 15) * 8;
        short8_t v = *reinterpret_cast<const short8_t*>(A + (size_t)(rowA0 + r) * 128 + c);
        *reinterpret_cast<short8_t*>(&As[r][c]) = v;
    }
    // Stage B tile: 64 rows x 128 bf16
    #pragma unroll
    for (int it = 0; it < 4; ++it) {
        int idx = it * 256 + t;
        int r = idx >> 4;
        int c = (idx & 15) * 8;
        short8_t v = *reinterpret_cast<const short8_t*>(B + (size_t)(rowB0 + r) * 128 + c);
        *reinterpret_cast<short8_t*>(&Bs[r][c]) = v;
    }
    if (t < BM) xq_s[t] = xsq[rowA0 + t];
    if (t < BN) pq_s[t] = psq[rowB0 + t];
    __syncthreads();

    int wave = t >> 6;
    int lane = t & 63;
    int wm = (wave >> 1) * 64;   // wave M offset: 0 / 64
    int wn = (wave & 1) * 32;    // wave N offset: 0 / 32
    int lr = lane & 15;
    int lk = (lane >> 4) * 8;

    f32x4 acc[4][2] = {};
    #pragma unroll
    for (int ks = 0; ks < 4; ++ks) {
        int k0 = ks * 32 + lk;
        short8_t a[4], b[2];
        #pragma unroll
        for (int mi = 0; mi < 4; ++mi)
            a[mi] = *reinterpret_cast<const short8_t*>(&As[wm + mi * 16 + lr][k0]);
        #pragma unroll
        for (int ni = 0; ni < 2; ++ni)
            b[ni] = *reinterpret_cast<const short8_t*>(&Bs[wn + ni * 16 + lr][k0]);
        #pragma unroll
        for (int mi = 0; mi < 4; ++mi)
            #pragma unroll
            for (int ni = 0; ni < 2; ++ni)
                acc[mi][ni] = __builtin_amdgcn_mfma_f32_16x16x32_bf16(
                        a[mi], b[ni], acc[mi][ni], 0, 0, 0);
    }

    // Epilogue: C/D layout col=lane&15, row=(lane>>4)*4+j  [m89]
    int mrow_base = (lane >> 4) * 4;
    #pragma unroll
    for (int mi = 0; mi < 4; ++mi) {
        #pragma unroll
        for (int ni = 0; ni < 2; ++ni) {
            int cl = wn + ni * 16 + lr;
            int c = rowB0 + cl;
            if (c < 1000) {
                float pq = pq_s[cl];
                #pragma unroll
                for (int j = 0; j < 4; ++j) {
                    int ml = wm + mi * 16 + mrow_base + j;
                    int m = rowA0 + ml;
                    out[(size_t)m * 1000 + c] = 2.f * acc[mi][ni][j] - xq_s[ml] - pq;
                }
            }
        }
    }
}

// Correct-but-slow fallback if workspace is too small.
__global__ __launch_bounds__(256) void naive_kernel(
        const float* __restrict__ x, const float* __restrict__ p,
        float* __restrict__ out) {
    long long idx = (long long)blockIdx.x * 256 + threadIdx.x;
    if (idx >= (long long)8192 * 1000) return;
    int n = (int)(idx / 1000);
    int c = (int)(idx % 1000);
    const float4* xr = reinterpret_cast<const float4*>(x + (size_t)n * 128);
    const float4* pr = reinterpret_cast<const float4*>(p + (size_t)c * 128);
    float d = 0.f;
    #pragma unroll
    for (int i = 0; i < 32; ++i) {
        float4 a = xr[i], b = pr[i];
        float dx = a.x - b.x, dy = a.y - b.y, dz = a.z - b.z, dw = a.w - b.w;
        d += dx * dx + dy * dy + dz * dz + dw * dw;
    }
    out[idx] = -d;
}

extern "C" void kernel_launch(void* const* d_in, const int* in_sizes, int n_in,
                              void* d_out, int out_size, void* d_ws, size_t ws_size,
                              hipStream_t stream) {
    const float* x = (const float*)d_in[0];   // (8192, 128) f32
    const float* p = (const float*)d_in[1];   // (1000, 128) f32
    float* out = (float*)d_out;               // (8192, 1000) f32

    const size_t xb_elems = (size_t)8192 * 128;
    const size_t pb_elems = (size_t)1024 * 128;
    const size_t need = xb_elems * 2 + pb_elems * 2 + 8192 * 4 + 1024 * 4;

    if (ws_size >= need) {
        unsigned short* xb = (unsigned short*)d_ws;
        unsigned short* pb = xb + xb_elems;
        float* xsq = (float*)(pb + pb_elems);
        float* psq = xsq + 8192;
        prep_kernel<<<1024, 256, 0, stream>>>(x, xb, xsq, 8192, 8192);
        prep_kernel<<<128, 256, 0, stream>>>(p, pb, psq, 1000, 1024);
        gemm_kernel<<<1024, 256, 0, stream>>>(xb, pb, xsq, psq, out);
    } else {
        naive_kernel<<<((size_t)8192 * 1000 + 255) / 256, 256, 0, stream>>>(x, p, out);
    }
}